// Round 2
// baseline (612.886 us; speedup 1.0000x reference)
//
#include <hip/hip_runtime.h>
#include <hip/hip_bf16.h>
#include <cstdio>

// ---------------------------------------------------------------------------
// Attn_59940563583594: hidden[32,1024,768] -> QKV -> causal attn (no 1/sqrt(d))
//                      -> relu MLP(768->64) -> out[32,1024,2] fp32
// Numerics: f16 storage/MFMA for hidden/W/q/k (logit err ~0.0024 << budget),
//           no-max softmax (exp clamped at 80, unnormalized p in bf16,
//           fp32 row sums, normalize in PV epilogue), bf16 PV + MLP.
// Workspace: 210 MB with aliasing (h16/W16 -> p_u; q16 -> h).
// ---------------------------------------------------------------------------

typedef _Float16 f16;
typedef f16    f16x8 __attribute__((ext_vector_type(8)));
typedef f16    f16x4 __attribute__((ext_vector_type(4)));
typedef __bf16 bfx8  __attribute__((ext_vector_type(8)));
typedef float  f32x4 __attribute__((ext_vector_type(4)));

#define MFMA_F16(a,b,c)  __builtin_amdgcn_mfma_f32_16x16x32_f16((a),(b),(c),0,0,0)
#define MFMA_BF16(a,b,c) __builtin_amdgcn_mfma_f32_16x16x32_bf16((a),(b),(c),0,0,0)

static constexpr int LDA = 40;   // LDS row stride (f16/bf16) for 32-wide K tiles
static constexpr int LDT = 136;  // transpose buffer stride

// ---------------- fp32 -> f16 convert ---------------------------------------
__global__ __launch_bounds__(256) void cvt_f32_f16(
    const float* __restrict__ x, f16* __restrict__ y, int n)
{
    int base = (blockIdx.x * 256 + threadIdx.x) * 4;
    if (base >= n) return;
    f32x4 v = *(const f32x4*)(x + base);
    f16x4 o;
    #pragma unroll
    for (int e = 0; e < 4; ++e) o[e] = (f16)v[e];
    *(f16x4*)(y + base) = o;
}

// ---------------- K1a: q,k projections (f16 NT GEMM, M=32768 N=768 K=768) ---
__global__ __launch_bounds__(256) void qk_kernel(
    const f16* __restrict__ h16, const f16* __restrict__ wq, const f16* __restrict__ wk,
    const float* __restrict__ bq, const float* __restrict__ bk,
    f16* __restrict__ q16, f16* __restrict__ k16)
{
    const int z = blockIdx.z;
    const f16* W = z ? wk : wq;
    const float* bias = z ? bk : bq;
    f16* out = z ? k16 : q16;

    __shared__ alignas(16) f16 As[128 * LDA];
    __shared__ alignas(16) f16 Bs[128 * LDA];

    const int t = threadIdx.x, lane = t & 63, wave = t >> 6;
    const int wm = (wave & 1) * 64, wn = (wave >> 1) * 64;
    const int quad = lane >> 4, l16 = lane & 15;
    const int m0 = blockIdx.y * 128, n0 = blockIdx.x * 128;

    f32x4 acc[4][4] = {};
    for (int k0 = 0; k0 < 768; k0 += 32) {
        #pragma unroll
        for (int i = 0; i < 2; ++i) {
            int idx = t + i * 256;
            int r = idx >> 2, c = (idx & 3) * 8;
            *(f16x8*)&As[r * LDA + c] = *(const f16x8*)&h16[(size_t)(m0 + r) * 768 + k0 + c];
            *(f16x8*)&Bs[r * LDA + c] = *(const f16x8*)&W[(size_t)(n0 + r) * 768 + k0 + c];
        }
        __syncthreads();
        f16x8 af[4], bg[4];
        #pragma unroll
        for (int i = 0; i < 4; ++i) {
            af[i] = *(const f16x8*)&As[(wm + i * 16 + l16) * LDA + quad * 8];
            bg[i] = *(const f16x8*)&Bs[(wn + i * 16 + l16) * LDA + quad * 8];
        }
        #pragma unroll
        for (int i = 0; i < 4; ++i)
            #pragma unroll
            for (int j = 0; j < 4; ++j)
                acc[i][j] = MFMA_F16(af[i], bg[j], acc[i][j]);
        __syncthreads();
    }
    #pragma unroll
    for (int j = 0; j < 4; ++j) {
        int col = n0 + wn + j * 16 + l16;
        float bb = bias[col];
        #pragma unroll
        for (int i = 0; i < 4; ++i)
            #pragma unroll
            for (int r = 0; r < 4; ++r) {
                int row = m0 + wm + i * 16 + quad * 4 + r;  // D: col=lane&15, row=quad*4+reg
                out[(size_t)row * 768 + col] = (f16)(acc[i][j][r] + bb);
            }
    }
}

// ---------------- K1b: v projection -> vT[b,e,s] bf16 (LDS transpose) -------
__global__ __launch_bounds__(256) void v_kernel(
    const f16* __restrict__ h16, const f16* __restrict__ wv, const float* __restrict__ bv,
    __bf16* __restrict__ vT)
{
    __shared__ alignas(16) f16 As[128 * LDA];
    __shared__ alignas(16) f16 Bs[128 * LDA];
    __shared__ alignas(16) __bf16 Tb[128 * LDT];

    const int t = threadIdx.x, lane = t & 63, wave = t >> 6;
    const int wm = (wave & 1) * 64, wn = (wave >> 1) * 64;
    const int quad = lane >> 4, l16 = lane & 15;
    const int m0 = blockIdx.y * 128, n0 = blockIdx.x * 128;

    f32x4 acc[4][4] = {};
    for (int k0 = 0; k0 < 768; k0 += 32) {
        #pragma unroll
        for (int i = 0; i < 2; ++i) {
            int idx = t + i * 256;
            int r = idx >> 2, c = (idx & 3) * 8;
            *(f16x8*)&As[r * LDA + c] = *(const f16x8*)&h16[(size_t)(m0 + r) * 768 + k0 + c];
            *(f16x8*)&Bs[r * LDA + c] = *(const f16x8*)&wv[(size_t)(n0 + r) * 768 + k0 + c];
        }
        __syncthreads();
        f16x8 af[4], bg[4];
        #pragma unroll
        for (int i = 0; i < 4; ++i) {
            af[i] = *(const f16x8*)&As[(wm + i * 16 + l16) * LDA + quad * 8];
            bg[i] = *(const f16x8*)&Bs[(wn + i * 16 + l16) * LDA + quad * 8];
        }
        #pragma unroll
        for (int i = 0; i < 4; ++i)
            #pragma unroll
            for (int j = 0; j < 4; ++j)
                acc[i][j] = MFMA_F16(af[i], bg[j], acc[i][j]);
        __syncthreads();
    }
    // write v^T tile into LDS: Tb[e_local][s_local]
    #pragma unroll
    for (int j = 0; j < 4; ++j) {
        int el = wn + j * 16 + l16;
        float bb = bv[n0 + el];
        #pragma unroll
        for (int i = 0; i < 4; ++i)
            #pragma unroll
            for (int r = 0; r < 4; ++r) {
                int sl = wm + i * 16 + quad * 4 + r;
                Tb[el * LDT + sl] = (__bf16)(acc[i][j][r] + bb);
            }
    }
    __syncthreads();
    const size_t bofs = (size_t)(m0 >> 10) * 768;
    const int s0 = m0 & 1023;
    const int ch = (t & 15) * 8;
    #pragma unroll
    for (int p = 0; p < 8; ++p) {
        int r = (t >> 4) + p * 16;
        bfx8 val = *(const bfx8*)&Tb[r * LDT + ch];
        *(bfx8*)&vT[(bofs + n0 + r) * 1024 + s0 + ch] = val;
    }
}

// ---------------- K2: p_u = exp(q@k^T + mask), bf16; fp32 rowsum partials ---
__global__ __launch_bounds__(256) void logits_kernel(
    const f16* __restrict__ q16, const f16* __restrict__ k16,
    const float* __restrict__ amask, __bf16* __restrict__ pu, float* __restrict__ psum)
{
    const int b = blockIdx.z, nt = blockIdx.x;
    const int m0 = blockIdx.y * 128, n0 = nt * 128;
    const int t = threadIdx.x;
    const size_t pb = (size_t)b << 20;

    if (n0 > m0) {  // fully masked tile: p = 0 exactly
        int r = t >> 1, half = t & 1;
        bfx8 zv;
        #pragma unroll
        for (int e = 0; e < 8; ++e) zv[e] = (__bf16)0.f;
        #pragma unroll
        for (int c = 0; c < 8; ++c)
            *(bfx8*)&pu[pb + (size_t)(m0 + r) * 1024 + n0 + half * 64 + c * 8] = zv;
        if (t < 128) psum[((size_t)b * 1024 + m0 + t) * 8 + nt] = 0.f;
        return;
    }

    __shared__ alignas(16) f16 As[128 * LDA];
    __shared__ alignas(16) f16 Bs[128 * LDA];
    __shared__ float rs[2][128];

    const int lane = t & 63, wave = t >> 6;
    const int wm = (wave & 1) * 64, wn = (wave >> 1) * 64;
    const int quad = lane >> 4, l16 = lane & 15;
    const size_t qb = (size_t)b * 1024 * 768;

    f32x4 acc[4][4] = {};
    for (int k0 = 0; k0 < 768; k0 += 32) {
        #pragma unroll
        for (int i = 0; i < 2; ++i) {
            int idx = t + i * 256;
            int r = idx >> 2, c = (idx & 3) * 8;
            *(f16x8*)&As[r * LDA + c] = *(const f16x8*)&q16[qb + (size_t)(m0 + r) * 768 + k0 + c];
            *(f16x8*)&Bs[r * LDA + c] = *(const f16x8*)&k16[qb + (size_t)(n0 + r) * 768 + k0 + c];
        }
        __syncthreads();
        f16x8 af[4], bg[4];
        #pragma unroll
        for (int i = 0; i < 4; ++i) {
            af[i] = *(const f16x8*)&As[(wm + i * 16 + l16) * LDA + quad * 8];
            bg[i] = *(const f16x8*)&Bs[(wn + i * 16 + l16) * LDA + quad * 8];
        }
        #pragma unroll
        for (int i = 0; i < 4; ++i)
            #pragma unroll
            for (int j = 0; j < 4; ++j)
                acc[i][j] = MFMA_F16(af[i], bg[j], acc[i][j]);
        __syncthreads();
    }

    float rp[4][4] = {};  // row partials (sum over this tile's 128 cols)
    #pragma unroll
    for (int j = 0; j < 4; ++j) {
        int col = n0 + wn + j * 16 + l16;
        float am = (1.0f - amask[b * 1024 + col]) * -10000.0f;
        #pragma unroll
        for (int i = 0; i < 4; ++i)
            #pragma unroll
            for (int r = 0; r < 4; ++r) {
                int row = m0 + wm + i * 16 + quad * 4 + r;
                float s = acc[i][j][r] + am;
                float pval = (col <= row) ? __expf(fminf(s, 80.0f)) : 0.0f;
                pu[pb + (size_t)row * 1024 + col] = (__bf16)pval;
                rp[i][r] += pval;
            }
    }
    #pragma unroll
    for (int i = 0; i < 4; ++i)
        #pragma unroll
        for (int r = 0; r < 4; ++r) {
            float v = rp[i][r];
            v += __shfl_xor(v, 1, 64);
            v += __shfl_xor(v, 2, 64);
            v += __shfl_xor(v, 4, 64);
            v += __shfl_xor(v, 8, 64);   // sum over l16 group
            if (l16 == 0) rs[wn >> 6][wm + i * 16 + quad * 4 + r] = v;
        }
    __syncthreads();
    if (t < 128)
        psum[((size_t)b * 1024 + m0 + t) * 8 + nt] = rs[0][t] + rs[1][t];
}

// ---------------- K3: h = (p_u @ v) / rowsum, bf16 --------------------------
__global__ __launch_bounds__(256) void pv_kernel(
    const __bf16* __restrict__ pu, const __bf16* __restrict__ vT,
    const float* __restrict__ psum, __bf16* __restrict__ h)
{
    const int b = blockIdx.z;
    const int m0 = blockIdx.y * 128, n0 = blockIdx.x * 128;
    const int t = threadIdx.x, lane = t & 63, wave = t >> 6;
    const int wm = (wave & 1) * 64, wn = (wave >> 1) * 64;
    const int quad = lane >> 4, l16 = lane & 15;
    const size_t pb = (size_t)b << 20;
    const size_t vb = (size_t)b * 768 * 1024;

    __shared__ alignas(16) __bf16 As[128 * LDA];
    __shared__ alignas(16) __bf16 Bs[128 * LDA];
    __shared__ float invl[128];

    if (t < 128) {
        const float* pr = &psum[((size_t)b * 1024 + m0 + t) * 8];
        f32x4 a = *(const f32x4*)pr, c = *(const f32x4*)(pr + 4);
        invl[t] = 1.0f / (a[0] + a[1] + a[2] + a[3] + c[0] + c[1] + c[2] + c[3]);
    }

    f32x4 acc[4][4] = {};
    const int kend = m0 + 128;  // p_u is exactly 0 above the diagonal
    for (int k0 = 0; k0 < kend; k0 += 32) {
        #pragma unroll
        for (int i = 0; i < 2; ++i) {
            int idx = t + i * 256;
            int r = idx >> 2, c = (idx & 3) * 8;
            *(bfx8*)&As[r * LDA + c] = *(const bfx8*)&pu[pb + (size_t)(m0 + r) * 1024 + k0 + c];
            *(bfx8*)&Bs[r * LDA + c] = *(const bfx8*)&vT[vb + (size_t)(n0 + r) * 1024 + k0 + c];
        }
        __syncthreads();
        bfx8 af[4], bg[4];
        #pragma unroll
        for (int i = 0; i < 4; ++i) {
            af[i] = *(const bfx8*)&As[(wm + i * 16 + l16) * LDA + quad * 8];
            bg[i] = *(const bfx8*)&Bs[(wn + i * 16 + l16) * LDA + quad * 8];
        }
        #pragma unroll
        for (int i = 0; i < 4; ++i)
            #pragma unroll
            for (int j = 0; j < 4; ++j)
                acc[i][j] = MFMA_BF16(af[i], bg[j], acc[i][j]);
        __syncthreads();
    }
    #pragma unroll
    for (int j = 0; j < 4; ++j) {
        int col = n0 + wn + j * 16 + l16;
        #pragma unroll
        for (int i = 0; i < 4; ++i)
            #pragma unroll
            for (int r = 0; r < 4; ++r) {
                int rl = wm + i * 16 + quad * 4 + r;
                h[((size_t)b * 1024 + m0 + rl) * 768 + col] = (__bf16)(acc[i][j][r] * invl[rl]);
            }
    }
}

// ---------------- K4: out = relu(h @ W1^T + b1) @ W2^T + b2 -----------------
__global__ __launch_bounds__(256) void mlp_kernel(
    const __bf16* __restrict__ h, const float* __restrict__ W1, const float* __restrict__ b1,
    const float* __restrict__ W2, const float* __restrict__ b2, float* __restrict__ out)
{
    const int wave = threadIdx.x >> 6, lane = threadIdx.x & 63;
    const int quad = lane >> 4, l16 = lane & 15;
    const int m0 = blockIdx.x * 64 + wave * 16;

    f32x4 acc[4] = {};
    for (int k0 = 0; k0 < 768; k0 += 32) {
        bfx8 af = *(const bfx8*)&h[(size_t)(m0 + l16) * 768 + k0 + quad * 8];
        #pragma unroll
        for (int j = 0; j < 4; ++j) {
            const float* wp = W1 + (size_t)(j * 16 + l16) * 768 + k0 + quad * 8;
            f32x4 w0 = *(const f32x4*)wp;
            f32x4 w1 = *(const f32x4*)(wp + 4);
            bfx8 bg;
            #pragma unroll
            for (int e = 0; e < 4; ++e) { bg[e] = (__bf16)w0[e]; bg[e + 4] = (__bf16)w1[e]; }
            acc[j] = MFMA_BF16(af, bg, acc[j]);
        }
    }
    float part[4][2] = {};
    #pragma unroll
    for (int j = 0; j < 4; ++j) {
        int c = j * 16 + l16;
        float bb = b1[c];
        float w20 = W2[c], w21 = W2[64 + c];
        #pragma unroll
        for (int r = 0; r < 4; ++r) {
            float x = fmaxf(acc[j][r] + bb, 0.f);
            part[r][0] += x * w20;
            part[r][1] += x * w21;
        }
    }
    #pragma unroll
    for (int off = 1; off < 16; off <<= 1)
        #pragma unroll
        for (int r = 0; r < 4; ++r) {
            part[r][0] += __shfl_xor(part[r][0], off, 64);
            part[r][1] += __shfl_xor(part[r][1], off, 64);
        }
    if (l16 == 0) {
        #pragma unroll
        for (int r = 0; r < 4; ++r) {
            int row = m0 + quad * 4 + r;
            out[(size_t)row * 2 + 0] = part[r][0] + b2[0];
            out[(size_t)row * 2 + 1] = part[r][1] + b2[1];
        }
    }
}

// ---------------------------------------------------------------------------
extern "C" void kernel_launch(void* const* d_in, const int* in_sizes, int n_in,
                              void* d_out, int out_size, void* d_ws, size_t ws_size,
                              hipStream_t stream)
{
    const float* hidden = (const float*)d_in[0];
    const float* amask  = (const float*)d_in[1];
    const float* Wk = (const float*)d_in[2];
    const float* bk = (const float*)d_in[3];
    const float* Wq = (const float*)d_in[4];
    const float* bq = (const float*)d_in[5];
    const float* Wv = (const float*)d_in[6];
    const float* bv = (const float*)d_in[7];
    const float* W1 = (const float*)d_in[8];
    const float* b1 = (const float*)d_in[9];
    const float* W2 = (const float*)d_in[10];
    const float* b2 = (const float*)d_in[11];
    float* out = (float*)d_out;

    char* ws = (char*)d_ws;
    const size_t MB = 1024 * 1024;
    // Phase 1 (qkv): h16 @0 (48MB), w16 @48MB (3.4MB)  [dead after qkv]
    // Phase 2 (logits): pu @0 (64MB, aliases phase1), psum @64MB (1MB)
    // q16 @66MB (48), k16 @114MB (48), vT @162MB (48)
    // Phase 3 (pv/mlp): h @66MB (aliases q16, dead after logits)
    f16* h16 = (f16*)ws;
    f16* wq16 = (f16*)(ws + 48 * MB);
    f16* wk16 = wq16 + 589824;
    f16* wv16 = wk16 + 589824;
    __bf16* pu  = (__bf16*)ws;
    float*  psum = (float*)(ws + 64 * MB);
    f16* q16 = (f16*)(ws + 66 * MB);
    f16* k16 = (f16*)(ws + 114 * MB);
    __bf16* vT = (__bf16*)(ws + 162 * MB);
    __bf16* h  = (__bf16*)(ws + 66 * MB);
    const size_t NEED = 210 * MB;
    if (ws_size < NEED) {
        fprintf(stderr, "[Attn kernel] ws too small: %zu < %zu — skipping launches\n",
                ws_size, NEED);
        return;
    }

    cvt_f32_f16<<<24576, 256, 0, stream>>>(hidden, h16, 25165824);
    cvt_f32_f16<<<576, 256, 0, stream>>>(Wq, wq16, 589824);
    cvt_f32_f16<<<576, 256, 0, stream>>>(Wk, wk16, 589824);
    cvt_f32_f16<<<576, 256, 0, stream>>>(Wv, wv16, 589824);

    qk_kernel<<<dim3(6, 256, 2), 256, 0, stream>>>(h16, wq16, wk16, bq, bk, q16, k16);
    v_kernel<<<dim3(6, 256), 256, 0, stream>>>(h16, wv16, bv, vT);
    logits_kernel<<<dim3(8, 8, 32), 256, 0, stream>>>(q16, k16, amask, pu, psum);
    pv_kernel<<<dim3(6, 8, 32), 256, 0, stream>>>(pu, vT, psum, h);
    mlp_kernel<<<512, 256, 0, stream>>>(h, W1, b1, W2, b2, out);
}